// Round 4
// baseline (365.785 us; speedup 1.0000x reference)
//
#include <hip/hip_runtime.h>
#include <math.h>

#define BS   32
#define A_N  8400
#define G_N  64
#define NC_N 80
#define TK   10
#define DROWS 22   // LDS delta ring rows (ranks visited monotonically -> refill)

static __device__ __forceinline__ bool lexless(float v1, int i1, float v2, int i2) {
    return (v1 < v2) || (v1 == v2 && i1 < i2);
}
static __device__ __forceinline__ float fdiv(float n, float d) {
    return n * __builtin_amdgcn_rcpf(d);
}
static __device__ __forceinline__ unsigned sortable(float f) {
    unsigned u = __float_as_uint(f);
    return (u & 0x80000000u) ? ~u : (u | 0x80000000u);
}

// ---------------------------------------------------------------------------
// Kernel 1: fused cls-cost + CIoU + gating  ->  cost[b][g][a]
// 256 threads, thread = one anchor. S via grouped-product logs.
// Per-distinct-class delta in a 22-row LDS ring (per-thread private columns,
// no barriers); ring refilled by re-streaming the (L2-warm) score row when
// the g-loop's monotone rank pointer leaves the window. LDS ~26.7 KB -> 6
// blocks/CU (vs 3 at R3's 49.6 KB).
// ---------------------------------------------------------------------------
__global__ __launch_bounds__(256, 6)
void k_cost(const float* __restrict__ pred_boxes,   // [BS][A][4]
            const float* __restrict__ gt_boxes,     // [BS][G][4]
            const float* __restrict__ pred_scores,  // [BS][A][NC]
            const int*   __restrict__ gt_labels,    // [BS][G]
            float* __restrict__ cost)               // [BS][G][A]
{
    __shared__ float s_gx1[G_N], s_gy1[G_N], s_gx2[G_N], s_gy2[G_N];
    __shared__ float s_gsx[G_N], s_gsy[G_N];
    __shared__ float s_glx[G_N], s_gly[G_N], s_ghx[G_N], s_ghy[G_N];
    __shared__ float s_area2[G_N], s_atg[G_N];
    __shared__ int   s_lab[G_N];
    __shared__ int   s_ord[G_N];
    __shared__ int   s_pres[NC_N];
    __shared__ int   s_rank[NC_N];
    __shared__ float s_delta[DROWS * 256];

    const float EPSF = 1e-9f;
    const int t = threadIdx.x;
    const int b = blockIdx.y;
    const int a = blockIdx.x * 256 + t;

    if (t < G_N) {
        const float4 gb = ((const float4*)gt_boxes)[b * G_N + t];
        const float gx1 = gb.x, gy1 = gb.y, gx2 = gb.z, gy2 = gb.w;
        s_gx1[t] = gx1; s_gy1[t] = gy1; s_gx2[t] = gx2; s_gy2[t] = gy2;
        const float sx = gx1 + gx2, sy = gy1 + gy2;
        s_gsx[t] = sx; s_gsy[t] = sy;
        const float cx = sx / 2.0f, cy = sy / 2.0f;
        s_glx[t] = cx - 2.5f; s_ghx[t] = cx + 2.5f;
        s_gly[t] = cy - 2.5f; s_ghy[t] = cy + 2.5f;
        const float w2 = gx2 - gx1;
        const float h2 = (gy2 - gy1) + EPSF;
        s_area2[t] = w2 * h2;
        s_atg[t]   = atanf(w2 / h2);
        s_lab[t]   = gt_labels[b * G_N + t];
    }
    __syncthreads();
    if (t < NC_N) {
        int pr = 0;
        for (int j = 0; j < G_N; ++j) pr |= (s_lab[j] == t);
        s_pres[t] = pr;
    }
    if (t < G_N) {
        const int myl = s_lab[t];
        int rank = 0;
        for (int j = 0; j < G_N; ++j) {
            const int lj = s_lab[j];
            rank += (lj < myl) || (lj == myl && j < t);
        }
        s_ord[rank] = t;
    }
    __syncthreads();
    if (t < NC_N) {
        int r = 0;
        for (int c = 0; c < t; ++c) r += s_pres[c];
        s_rank[t] = s_pres[t] ? r : -1;
    }
    __syncthreads();
    if (a >= A_N) return;

    const float* prow = pred_scores + ((size_t)b * A_N + a) * NC_N;
    const float4* p4 = (const float4*)prow;
    const float LO = 1e-7f;
    const float HI = (float)(1.0 - 1e-7);

    // --- pass 1: grouped-product S + capture ranks [0, DROWS)
    float prod = 1.0f, Sacc = 0.0f;
    for (int c4 = 0; c4 < NC_N / 4; ++c4) {
        const float4 pv = p4[c4];
        const float ps[4] = {pv.x, pv.y, pv.z, pv.w};
        #pragma unroll
        for (int j = 0; j < 4; ++j) {
            const float pc = fminf(fmaxf(ps[j], LO), HI);
            const float q  = 1.0f - pc;
            prod *= q;
            const int r = s_rank[c4 * 4 + j];
            if (r >= 0 && r < DROWS)
                s_delta[r * 256 + t] = logf(q * __builtin_amdgcn_rcpf(pc));
        }
        if (c4 & 1) { Sacc += logf(prod); prod = 1.0f; }
    }
    const float S = -Sacc;

    const float4 pb = ((const float4*)pred_boxes)[(size_t)b * A_N + a];
    const float pcx  = (pb.x + pb.z) / 2.0f;
    const float pcy  = (pb.y + pb.w) / 2.0f;
    const float w1   = pb.z - pb.x;
    const float h1   = (pb.w - pb.y) + EPSF;
    const float area1 = w1 * h1;
    const float atp  = atanf(w1 / h1);
    const float KPI  = (float)(4.0 / (M_PI * M_PI));

    float* crow = cost + (size_t)b * G_N * A_N + a;
    int   cur_c = -1, krank = -1, base = 0;
    float delta_c = 0.0f;
    for (int k = 0; k < G_N; ++k) {
        const int g = s_ord[k];           // uniform across block
        const int c = s_lab[g];           // ascending; uniform
        if (c != cur_c) {
            ++krank;
            if (krank >= base + DROWS) {  // uniform: refill ring window
                base += DROWS;
                for (int c4 = 0; c4 < NC_N / 4; ++c4) {
                    const float4 pv = p4[c4];     // L2/L3-warm re-stream
                    const float ps[4] = {pv.x, pv.y, pv.z, pv.w};
                    #pragma unroll
                    for (int j = 0; j < 4; ++j) {
                        const int r = s_rank[c4 * 4 + j];
                        if (r >= base && r < base + DROWS) {
                            const float pc = fminf(fmaxf(ps[j], LO), HI);
                            s_delta[(r - base) * 256 + t] =
                                logf((1.0f - pc) * __builtin_amdgcn_rcpf(pc));
                        }
                    }
                }
            }
            delta_c = s_delta[(krank - base) * 256 + t];
            cur_c = c;
        }

        const float gx1 = s_gx1[g], gy1 = s_gy1[g], gx2 = s_gx2[g], gy2 = s_gy2[g];
        const bool inb  = (pcx > gx1) && (pcy > gy1) && (gx2 > pcx) && (gy2 > pcy);
        const bool inc  = (pcx > s_glx[g]) && (pcy > s_gly[g]) &&
                          (s_ghx[g] > pcx) && (s_ghy[g] > pcy);
        const bool both = inb && inc;

        const float iw    = fmaxf(fminf(pb.z, gx2) - fmaxf(pb.x, gx1), 0.0f);
        const float ih    = fmaxf(fminf(pb.w, gy2) - fmaxf(pb.y, gy1), 0.0f);
        const float inter = iw * ih;
        const float uni   = ((area1 + s_area2[g]) - inter) + EPSF;
        const float iou   = fdiv(inter, uni);
        const float cw    = fmaxf(pb.z, gx2) - fminf(pb.x, gx1);
        const float ch    = fmaxf(pb.w, gy2) - fminf(pb.y, gy1);
        const float c2    = ((cw * cw) + (ch * ch)) + EPSF;
        const float dx    = (s_gsx[g] - pb.x) - pb.z;
        const float dy    = (s_gsy[g] - pb.y) - pb.w;
        const float d2    = ((dx * dx) + (dy * dy)) / 4.0f;
        const float dif   = s_atg[g] - atp;
        const float v     = KPI * (dif * dif);
        const float alpha = fdiv(v, (v - iou) + 1.0f);
        const float ciou  = iou - (fdiv(d2, c2) + v * alpha);

        const float cls   = S + delta_c;
        const float cst   = (cls + 3.0f * ciou) + (both ? 0.0f : 100000.0f);
        crow[(size_t)g * A_N] = cst;
    }
}

// ---------------------------------------------------------------------------
// Kernel 2: top-10 smallest (value, index) per (b,g) row of 8400
// ---------------------------------------------------------------------------
__global__ __launch_bounds__(256)
void k_topk(const float* __restrict__ cost, int* __restrict__ topk)
{
    __shared__ float s_wv[4][TK];
    __shared__ int   s_wi[4][TK];

    const int bg   = blockIdx.x;
    const int t    = threadIdx.x;
    const int lane = t & 63;
    const int wid  = t >> 6;
    const float* row = cost + (size_t)bg * A_N;
    const float FINF = __builtin_inff();

    float v[TK]; int id[TK];
    #pragma unroll
    for (int j = 0; j < TK; ++j) { v[j] = FINF; id[j] = 0x7FFFFFFF; }

    auto consider = [&](float c, int a) {
        if (lexless(c, a, v[TK - 1], id[TK - 1])) {
            v[TK - 1] = c; id[TK - 1] = a;
            #pragma unroll
            for (int j = TK - 2; j >= 0; --j) {
                const bool sw = lexless(v[j + 1], id[j + 1], v[j], id[j]);
                const float tv = v[j]; const int ti = id[j];
                v[j]      = sw ? v[j + 1] : v[j];
                id[j]     = sw ? id[j + 1] : id[j];
                v[j + 1]  = sw ? tv : v[j + 1];
                id[j + 1] = sw ? ti : id[j + 1];
            }
        }
    };

    const float4* row4 = (const float4*)row;
    for (int i = t; i < A_N / 4; i += 256) {
        const float4 c4 = row4[i];
        const int base = i * 4;
        consider(c4.x, base);
        consider(c4.y, base + 1);
        consider(c4.z, base + 2);
        consider(c4.w, base + 3);
    }

    #pragma unroll
    for (int r = 0; r < TK; ++r) {
        float bv = v[0]; int ba = id[0];
        #pragma unroll
        for (int off = 1; off < 64; off <<= 1) {
            const float ov = __shfl_xor(bv, off, 64);
            const int   oa = __shfl_xor(ba, off, 64);
            if (lexless(ov, oa, bv, ba)) { bv = ov; ba = oa; }
        }
        if (lane == 0) { s_wv[wid][r] = bv; s_wi[wid][r] = ba; }
        if (id[0] == ba) {
            #pragma unroll
            for (int j = 0; j < TK - 1; ++j) { v[j] = v[j + 1]; id[j] = id[j + 1]; }
            v[TK - 1] = FINF; id[TK - 1] = 0x7FFFFFFF;
        }
    }
    __syncthreads();

    if (wid == 0) {
        float cv = FINF; int ci = 0x7FFFFFFF;
        if (lane < 4 * TK) { cv = s_wv[lane / TK][lane % TK]; ci = s_wi[lane / TK][lane % TK]; }
        #pragma unroll
        for (int r = 0; r < TK; ++r) {
            float bv = cv; int ba = ci;
            #pragma unroll
            for (int off = 1; off < 64; off <<= 1) {
                const float ov = __shfl_xor(bv, off, 64);
                const int   oa = __shfl_xor(ba, off, 64);
                if (lexless(ov, oa, bv, ba)) { bv = ov; ba = oa; }
            }
            if (lane == 0) topk[bg * TK + r] = ba;
            if (ci == ba) { cv = FINF; ci = 0x7FFFFFFF; }
        }
    }
}

// ---------------------------------------------------------------------------
// Sparse final: final[b,:,a] = onehot(argmin_{g in members(a)} cost) or 0.
// (count==1 => argmin == the single member, so this equals the reference.)
// Phase 1: atomicMin of (sortable_cost<<6 | g) per (b,a) over topk entries.
// Phase 2: winning g writes 1.0f. final pre-zeroed by hipMemsetAsync.
// ---------------------------------------------------------------------------
__global__ __launch_bounds__(256)
void k_scatter1(const float* __restrict__ cost,
                const int*   __restrict__ topk,
                const unsigned char* __restrict__ mask_gt,
                unsigned long long* __restrict__ slot)   // [BS][A_N]
{
    const int e = blockIdx.x * 256 + threadIdx.x;
    if (e >= BS * G_N * TK) return;
    const int b = e / (G_N * TK);
    const int r = e % (G_N * TK);
    const int g = r / TK;
    if (!mask_gt[b * G_N + g]) return;
    const int a = topk[e];
    const float c = cost[((size_t)b * G_N + g) * A_N + a];
    const unsigned long long key = ((unsigned long long)sortable(c) << 6) | (unsigned)g;
    atomicMin(&slot[(size_t)b * A_N + a], key);
}

__global__ __launch_bounds__(256)
void k_scatter2(const int* __restrict__ topk,
                const unsigned char* __restrict__ mask_gt,
                const unsigned long long* __restrict__ slot,
                float* __restrict__ final_out)           // [BS][G][A]
{
    const int e = blockIdx.x * 256 + threadIdx.x;
    if (e >= BS * G_N * TK) return;
    const int b = e / (G_N * TK);
    const int r = e % (G_N * TK);
    const int g = r / TK;
    if (!mask_gt[b * G_N + g]) return;
    const int a = topk[e];
    if ((int)(slot[(size_t)b * A_N + a] & 63ull) == g)
        final_out[((size_t)b * G_N + g) * A_N + a] = 1.0f;
}

// ---------------------------------------------------------------------------
// Fallback dense final (used only if ws_size too small for slot array)
// ---------------------------------------------------------------------------
__global__ __launch_bounds__(256)
void k_final(const float* __restrict__ cost,
             const int*   __restrict__ topk,
             const unsigned char* __restrict__ mask_gt,
             float* __restrict__ final_out)
{
    __shared__ int s_top[G_N * TK];
    __shared__ int s_mask[G_N];

    const int t = threadIdx.x;
    const int b = blockIdx.y;
    const int a = blockIdx.x * 256 + t;

    for (int k = t; k < G_N * TK; k += 256) s_top[k] = topk[b * G_N * TK + k];
    if (t < G_N) s_mask[t] = (int)mask_gt[b * G_N + t];
    __syncthreads();
    if (a >= A_N) return;

    unsigned long long member = 0ull;
    int cnt = 0;
    float best = __builtin_inff();
    int bestg = 0;
    for (int g = 0; g < G_N; ++g) {
        bool m = false;
        if (s_mask[g]) {
            #pragma unroll
            for (int j = 0; j < TK; ++j) m = m || (s_top[g * TK + j] == a);
        }
        if (m) {
            member |= (1ull << g);
            ++cnt;
            const float c = cost[((size_t)b * G_N + g) * A_N + a];
            if (c < best) { best = c; bestg = g; }
        }
    }
    const bool ovl = cnt > 1;
    float* frow = final_out + (size_t)b * G_N * A_N + a;
    for (int g = 0; g < G_N; ++g) {
        const bool f = ovl ? (g == bestg) : (((member >> g) & 1ull) != 0ull);
        frow[(size_t)g * A_N] = f ? 1.0f : 0.0f;
    }
}

// ---------------------------------------------------------------------------
extern "C" void kernel_launch(void* const* d_in, const int* in_sizes, int n_in,
                              void* d_out, int out_size, void* d_ws, size_t ws_size,
                              hipStream_t stream)
{
    const float* pred_boxes  = (const float*)d_in[0];
    const float* gt_boxes    = (const float*)d_in[1];
    const unsigned char* mask_gt = (const unsigned char*)d_in[2];
    const float* pred_scores = (const float*)d_in[3];
    const int*   gt_labels   = (const int*)d_in[4];

    float* out_final = (float*)d_out;
    float* out_cost  = out_final + (size_t)BS * G_N * A_N;

    const size_t slot_bytes = (size_t)BS * A_N * sizeof(unsigned long long); // 2.15 MB
    const size_t topk_bytes = (size_t)BS * G_N * TK * sizeof(int);           // 80 KB
    unsigned long long* slot = (unsigned long long*)d_ws;
    int* topk_ws = (int*)((char*)d_ws + slot_bytes);
    const bool sparse_ok = ws_size >= slot_bytes + topk_bytes;
    if (!sparse_ok) topk_ws = (int*)d_ws;

    k_cost <<<dim3((A_N + 255) / 256, BS), 256, 0, stream>>>(
        pred_boxes, gt_boxes, pred_scores, gt_labels, out_cost);
    k_topk <<<dim3(BS * G_N), 256, 0, stream>>>(out_cost, topk_ws);

    if (sparse_ok) {
        hipMemsetAsync(out_final, 0, (size_t)BS * G_N * A_N * sizeof(float), stream);
        hipMemsetAsync(slot, 0xFF, slot_bytes, stream);
        const int NE = BS * G_N * TK;
        k_scatter1<<<dim3((NE + 255) / 256), 256, 0, stream>>>(
            out_cost, topk_ws, mask_gt, slot);
        k_scatter2<<<dim3((NE + 255) / 256), 256, 0, stream>>>(
            topk_ws, mask_gt, slot, out_final);
    } else {
        k_final<<<dim3((A_N + 255) / 256, BS), 256, 0, stream>>>(
            out_cost, topk_ws, mask_gt, out_final);
    }
}

// Round 5
// 334.674 us; speedup vs baseline: 1.0930x; 1.0930x over previous
//
#include <hip/hip_runtime.h>
#include <math.h>

#define BS   32
#define A_N  8400
#define G_N  64
#define NC_N 80
#define TK   10

static __device__ __forceinline__ float fdiv(float n, float d) {
    return n * __builtin_amdgcn_rcpf(d);
}
static __device__ __forceinline__ unsigned sortable(float f) {
    unsigned u = __float_as_uint(f);
    return (u & 0x80000000u) ? ~u : (u | 0x80000000u);
}

// ---------------------------------------------------------------------------
// Kernel 1: fused cls-cost + CIoU + gating  ->  cost[b][g][a]
// 256 threads, thread = one anchor.
// Pass 1: stream score row -> S (grouped-product logs, 10 logf).
// Pass 2: re-stream the SAME row in REVERSE (tail still L1-hot, reuse
// distance ~0); for each present class: delta once, then immediately emit
// all gts of that class (class segments in sorted order, LDS). No delta
// storage, no refill. LDS ~4 KB.
// ---------------------------------------------------------------------------
__global__ __launch_bounds__(256)
void k_cost(const float* __restrict__ pred_boxes,   // [BS][A][4]
            const float* __restrict__ gt_boxes,     // [BS][G][4]
            const float* __restrict__ pred_scores,  // [BS][A][NC]
            const int*   __restrict__ gt_labels,    // [BS][G]
            float* __restrict__ cost)               // [BS][G][A]
{
    __shared__ float s_gx1[G_N], s_gy1[G_N], s_gx2[G_N], s_gy2[G_N];
    __shared__ float s_gsx[G_N], s_gsy[G_N];
    __shared__ float s_glx[G_N], s_gly[G_N], s_ghx[G_N], s_ghy[G_N];
    __shared__ float s_area2[G_N], s_atg[G_N];
    __shared__ int   s_lab[G_N];
    __shared__ int   s_ord[G_N];                 // gts sorted by (label, idx)
    __shared__ int   s_seg0[NC_N], s_seg1[NC_N]; // class -> [start,end) in s_ord

    const float EPSF = 1e-9f;
    const int t = threadIdx.x;
    const int b = blockIdx.y;
    const int a = blockIdx.x * 256 + t;

    if (t < G_N) {
        const float4 gb = ((const float4*)gt_boxes)[b * G_N + t];
        const float gx1 = gb.x, gy1 = gb.y, gx2 = gb.z, gy2 = gb.w;
        s_gx1[t] = gx1; s_gy1[t] = gy1; s_gx2[t] = gx2; s_gy2[t] = gy2;
        const float sx = gx1 + gx2, sy = gy1 + gy2;
        s_gsx[t] = sx; s_gsy[t] = sy;
        const float cx = sx / 2.0f, cy = sy / 2.0f;
        s_glx[t] = cx - 2.5f; s_ghx[t] = cx + 2.5f;
        s_gly[t] = cy - 2.5f; s_ghy[t] = cy + 2.5f;
        const float w2 = gx2 - gx1;
        const float h2 = (gy2 - gy1) + EPSF;
        s_area2[t] = w2 * h2;
        s_atg[t]   = atanf(w2 / h2);
        s_lab[t]   = gt_labels[b * G_N + t];
    }
    __syncthreads();
    if (t < G_N) {   // unique rank by (label, idx)
        const int myl = s_lab[t];
        int rank = 0;
        for (int j = 0; j < G_N; ++j) {
            const int lj = s_lab[j];
            rank += (lj < myl) || (lj == myl && j < t);
        }
        s_ord[rank] = t;
    }
    if (t < NC_N) {  // class segment boundaries in the sorted order
        int lo = 0, hi = 0;
        for (int j = 0; j < G_N; ++j) {
            lo += (s_lab[j] <  t);
            hi += (s_lab[j] <= t);
        }
        s_seg0[t] = lo; s_seg1[t] = hi;
    }
    __syncthreads();
    if (a >= A_N) return;

    const float* prow = pred_scores + ((size_t)b * A_N + a) * NC_N;
    const float4* p4 = (const float4*)prow;
    const float LO = 1e-7f;
    const float HI = (float)(1.0 - 1e-7);

    // --- pass 1: grouped-product S (bit-identical to prior accepted rounds)
    float prod = 1.0f, Sacc = 0.0f;
    for (int c4 = 0; c4 < NC_N / 4; ++c4) {
        const float4 pv = p4[c4];
        const float ps[4] = {pv.x, pv.y, pv.z, pv.w};
        #pragma unroll
        for (int j = 0; j < 4; ++j) {
            const float pc = fminf(fmaxf(ps[j], LO), HI);
            prod *= (1.0f - pc);
        }
        if (c4 & 1) { Sacc += logf(prod); prod = 1.0f; }
    }
    const float S = -Sacc;

    const float4 pb = ((const float4*)pred_boxes)[(size_t)b * A_N + a];
    const float pcx  = (pb.x + pb.z) / 2.0f;
    const float pcy  = (pb.y + pb.w) / 2.0f;
    const float w1   = pb.z - pb.x;
    const float h1   = (pb.w - pb.y) + EPSF;
    const float area1 = w1 * h1;
    const float atp  = atanf(w1 / h1);
    const float KPI  = (float)(4.0 / (M_PI * M_PI));

    float* crow = cost + (size_t)b * G_N * A_N + a;

    // --- pass 2: reverse re-stream; per present class emit its gts
    for (int c4 = NC_N / 4 - 1; c4 >= 0; --c4) {
        if (s_seg1[c4 * 4 + 3] <= s_seg0[c4 * 4]) continue;  // group empty (uniform)
        const float4 pv = p4[c4];                             // L1-hot (LIFO)
        const float ps[4] = {pv.x, pv.y, pv.z, pv.w};
        #pragma unroll
        for (int j = 3; j >= 0; --j) {
            const int c  = c4 * 4 + j;
            const int lo = s_seg0[c], hi = s_seg1[c];
            if (lo >= hi) continue;                           // class absent (uniform)
            const float pc = fminf(fmaxf(ps[j], LO), HI);
            const float Sd = S + logf((1.0f - pc) * __builtin_amdgcn_rcpf(pc));
            for (int k = lo; k < hi; ++k) {
                const int g = s_ord[k];                       // uniform
                const float gx1 = s_gx1[g], gy1 = s_gy1[g];
                const float gx2 = s_gx2[g], gy2 = s_gy2[g];
                const bool inb  = (pcx > gx1) && (pcy > gy1) && (gx2 > pcx) && (gy2 > pcy);
                const bool inc  = (pcx > s_glx[g]) && (pcy > s_gly[g]) &&
                                  (s_ghx[g] > pcx) && (s_ghy[g] > pcy);
                const bool both = inb && inc;

                const float iw    = fmaxf(fminf(pb.z, gx2) - fmaxf(pb.x, gx1), 0.0f);
                const float ih    = fmaxf(fminf(pb.w, gy2) - fmaxf(pb.y, gy1), 0.0f);
                const float inter = iw * ih;
                const float uni   = ((area1 + s_area2[g]) - inter) + EPSF;
                const float iou   = fdiv(inter, uni);
                const float cw    = fmaxf(pb.z, gx2) - fminf(pb.x, gx1);
                const float ch    = fmaxf(pb.w, gy2) - fminf(pb.y, gy1);
                const float c2    = ((cw * cw) + (ch * ch)) + EPSF;
                const float dx    = (s_gsx[g] - pb.x) - pb.z;
                const float dy    = (s_gsy[g] - pb.y) - pb.w;
                const float d2    = ((dx * dx) + (dy * dy)) / 4.0f;
                const float dif   = s_atg[g] - atp;
                const float v     = KPI * (dif * dif);
                const float alpha = fdiv(v, (v - iou) + 1.0f);
                const float ciou  = iou - (fdiv(d2, c2) + v * alpha);

                const float cst   = (Sd + 3.0f * ciou) + (both ? 0.0f : 100000.0f);
                crow[(size_t)g * A_N] = cst;
            }
        }
    }
}

// ---------------------------------------------------------------------------
// Kernel 2: top-10 smallest per (b,g) row of 8400, u64 keys
// key = (sortable(cost) << 14) | a  — lexicographic (cost, a) in one compare.
// Per-thread sorted top-10 in registers; 2-stage shuffle-butterfly merge.
// ---------------------------------------------------------------------------
__global__ __launch_bounds__(256)
void k_topk(const float* __restrict__ cost, int* __restrict__ topk)
{
    __shared__ unsigned long long s_w[4][TK];

    const int bg   = blockIdx.x;
    const int t    = threadIdx.x;
    const int lane = t & 63;
    const int wid  = t >> 6;
    const float* row = cost + (size_t)bg * A_N;
    const unsigned long long UMAX = ~0ull;

    unsigned long long v[TK];
    #pragma unroll
    for (int j = 0; j < TK; ++j) v[j] = UMAX;

    auto consider = [&](float c, int idx) {
        const unsigned long long key =
            ((unsigned long long)sortable(c) << 14) | (unsigned)idx;
        if (key < v[TK - 1]) {
            v[TK - 1] = key;
            #pragma unroll
            for (int j = TK - 2; j >= 0; --j) {
                const bool sw = v[j + 1] < v[j];
                const unsigned long long tv = v[j];
                v[j]     = sw ? v[j + 1] : v[j];
                v[j + 1] = sw ? tv : v[j + 1];
            }
        }
    };

    // software-pipelined float4 stream (2100 vectors / 256 threads)
    const float4* row4 = (const float4*)row;
    const int NV = A_N / 4;
    float4 cur = make_float4(0.f, 0.f, 0.f, 0.f);
    if (t < NV) cur = row4[t];
    for (int i = t; i < NV; i += 256) {
        const int i2 = i + 256;
        float4 nxt = make_float4(0.f, 0.f, 0.f, 0.f);
        if (i2 < NV) nxt = row4[i2];
        const int base = i * 4;
        consider(cur.x, base);
        consider(cur.y, base + 1);
        consider(cur.z, base + 2);
        consider(cur.w, base + 3);
        cur = nxt;
    }

    // stage 1: per-wave 10-round butterfly-min + winner pop
    #pragma unroll
    for (int r = 0; r < TK; ++r) {
        unsigned long long bv = v[0];
        #pragma unroll
        for (int off = 1; off < 64; off <<= 1) {
            const unsigned long long ov = __shfl_xor(bv, off, 64);
            bv = (ov < bv) ? ov : bv;
        }
        if (lane == 0) s_w[wid][r] = bv;
        if (v[0] == bv) {                 // unique winner pops its sorted list
            #pragma unroll
            for (int j = 0; j < TK - 1; ++j) v[j] = v[j + 1];
            v[TK - 1] = UMAX;
        }
    }
    __syncthreads();

    // stage 2: wave 0 merges 4 sorted 10-lists (one candidate per lane)
    if (wid == 0) {
        unsigned long long cv = UMAX;
        if (lane < 4 * TK) cv = s_w[lane / TK][lane % TK];
        #pragma unroll
        for (int r = 0; r < TK; ++r) {
            unsigned long long bv = cv;
            #pragma unroll
            for (int off = 1; off < 64; off <<= 1) {
                const unsigned long long ov = __shfl_xor(bv, off, 64);
                bv = (ov < bv) ? ov : bv;
            }
            if (lane == 0) topk[bg * TK + r] = (int)(bv & 16383ull);
            if (cv == bv) cv = UMAX;
        }
    }
}

// ---------------------------------------------------------------------------
// Sparse final: final[b,:,a] = onehot(argmin_{g in members(a)} cost) or 0.
// ---------------------------------------------------------------------------
__global__ __launch_bounds__(256)
void k_scatter1(const float* __restrict__ cost,
                const int*   __restrict__ topk,
                const unsigned char* __restrict__ mask_gt,
                unsigned long long* __restrict__ slot)   // [BS][A_N]
{
    const int e = blockIdx.x * 256 + threadIdx.x;
    if (e >= BS * G_N * TK) return;
    const int b = e / (G_N * TK);
    const int r = e % (G_N * TK);
    const int g = r / TK;
    if (!mask_gt[b * G_N + g]) return;
    const int a = topk[e];
    const float c = cost[((size_t)b * G_N + g) * A_N + a];
    const unsigned long long key = ((unsigned long long)sortable(c) << 6) | (unsigned)g;
    atomicMin(&slot[(size_t)b * A_N + a], key);
}

__global__ __launch_bounds__(256)
void k_scatter2(const int* __restrict__ topk,
                const unsigned char* __restrict__ mask_gt,
                const unsigned long long* __restrict__ slot,
                float* __restrict__ final_out)           // [BS][G][A]
{
    const int e = blockIdx.x * 256 + threadIdx.x;
    if (e >= BS * G_N * TK) return;
    const int b = e / (G_N * TK);
    const int r = e % (G_N * TK);
    const int g = r / TK;
    if (!mask_gt[b * G_N + g]) return;
    const int a = topk[e];
    if ((int)(slot[(size_t)b * A_N + a] & 63ull) == g)
        final_out[((size_t)b * G_N + g) * A_N + a] = 1.0f;
}

// ---------------------------------------------------------------------------
// Fallback dense final (used only if ws_size too small for slot array)
// ---------------------------------------------------------------------------
__global__ __launch_bounds__(256)
void k_final(const float* __restrict__ cost,
             const int*   __restrict__ topk,
             const unsigned char* __restrict__ mask_gt,
             float* __restrict__ final_out)
{
    __shared__ int s_top[G_N * TK];
    __shared__ int s_mask[G_N];

    const int t = threadIdx.x;
    const int b = blockIdx.y;
    const int a = blockIdx.x * 256 + t;

    for (int k = t; k < G_N * TK; k += 256) s_top[k] = topk[b * G_N * TK + k];
    if (t < G_N) s_mask[t] = (int)mask_gt[b * G_N + t];
    __syncthreads();
    if (a >= A_N) return;

    unsigned long long member = 0ull;
    int cnt = 0;
    float best = __builtin_inff();
    int bestg = 0;
    for (int g = 0; g < G_N; ++g) {
        bool m = false;
        if (s_mask[g]) {
            #pragma unroll
            for (int j = 0; j < TK; ++j) m = m || (s_top[g * TK + j] == a);
        }
        if (m) {
            member |= (1ull << g);
            ++cnt;
            const float c = cost[((size_t)b * G_N + g) * A_N + a];
            if (c < best) { best = c; bestg = g; }
        }
    }
    const bool ovl = cnt > 1;
    float* frow = final_out + (size_t)b * G_N * A_N + a;
    for (int g = 0; g < G_N; ++g) {
        const bool f = ovl ? (g == bestg) : (((member >> g) & 1ull) != 0ull);
        frow[(size_t)g * A_N] = f ? 1.0f : 0.0f;
    }
}

// ---------------------------------------------------------------------------
extern "C" void kernel_launch(void* const* d_in, const int* in_sizes, int n_in,
                              void* d_out, int out_size, void* d_ws, size_t ws_size,
                              hipStream_t stream)
{
    const float* pred_boxes  = (const float*)d_in[0];
    const float* gt_boxes    = (const float*)d_in[1];
    const unsigned char* mask_gt = (const unsigned char*)d_in[2];
    const float* pred_scores = (const float*)d_in[3];
    const int*   gt_labels   = (const int*)d_in[4];

    float* out_final = (float*)d_out;
    float* out_cost  = out_final + (size_t)BS * G_N * A_N;

    const size_t slot_bytes = (size_t)BS * A_N * sizeof(unsigned long long);
    const size_t topk_bytes = (size_t)BS * G_N * TK * sizeof(int);
    unsigned long long* slot = (unsigned long long*)d_ws;
    int* topk_ws = (int*)((char*)d_ws + slot_bytes);
    const bool sparse_ok = ws_size >= slot_bytes + topk_bytes;
    if (!sparse_ok) topk_ws = (int*)d_ws;

    k_cost <<<dim3((A_N + 255) / 256, BS), 256, 0, stream>>>(
        pred_boxes, gt_boxes, pred_scores, gt_labels, out_cost);
    k_topk <<<dim3(BS * G_N), 256, 0, stream>>>(out_cost, topk_ws);

    if (sparse_ok) {
        hipMemsetAsync(out_final, 0, (size_t)BS * G_N * A_N * sizeof(float), stream);
        hipMemsetAsync(slot, 0xFF, slot_bytes, stream);
        const int NE = BS * G_N * TK;
        k_scatter1<<<dim3((NE + 255) / 256), 256, 0, stream>>>(
            out_cost, topk_ws, mask_gt, slot);
        k_scatter2<<<dim3((NE + 255) / 256), 256, 0, stream>>>(
            topk_ws, mask_gt, slot, out_final);
    } else {
        k_final<<<dim3((A_N + 255) / 256, BS), 256, 0, stream>>>(
            out_cost, topk_ws, mask_gt, out_final);
    }
}